// Round 4
// baseline (723.532 us; speedup 1.0000x reference)
//
#include <hip/hip_runtime.h>

// Problem constants
#define BB    16
#define CIN   32
#define LEN   1024
#define TT    64
#define COUT  64
#define KK    3

// Tiling: stage the FULL (ci, l-halo, 64t) tile once; zero steady-state syncs.
// TL=8 -> tile = 32ci x 10row x 256B = 81920 B = exactly 80 KiB -> 2 blocks/CU.
// Waves = t-quarters (16 t each); lanes = co-oct[3b] x l[3b].
#define TL       8
#define HALO     10                  // TL + 2
#define NTHREADS 256                 // 4 waves
#define NGRAN    (CIN * HALO * 16)   // 5120 16-B granules (full 64-t rows)
#define NROUND   (NGRAN / 64)        // 80 wave-rounds to fill
#define RPW      (NROUND / 4)        // 20 rounds per wave

// INVARIANT (bit-exact vs np ref, proven in earlier rounds): per output cell
// the conv sum is ONE sequential fmaf chain, k outer (0..2), ci inner (0..31),
// acc=0; LIF fp32: s=pot+a; p=s*0.9f; spk=(p>=0.25f); pot=spk?0:p.
// OOB halo terms participate as fmaf(0,w,acc) == reference zero-pad.

// Packed weights: wpk8[((g*3+k)*32+ci)*8 + j] = w[(g*8+j)][ci][k]
__device__ float wpk8[COUT * CIN * KK];
// Zero page for out-of-range halo rows (never written -> stays 0).
__device__ float zeros_g[64];

__global__ void repack_w(const float* __restrict__ w) {
    const int i = blockIdx.x * 256 + threadIdx.x;     // 6144 total
    if (i < COUT * CIN * KK) {
        const int j  = i & 7;
        const int ci = (i >> 3) & 31;
        const int gk = i >> 8;                        // g*3 + k
        const int k  = gk % 3;
        const int g  = gk / 3;
        wpk8[i] = w[((g * 8 + j) * CIN + ci) * KK + k];
    }
}

// 16-B async global->LDS (dest = wave-uniform base + lane*16; source per-lane).
#define GLD16(GP, LP) __builtin_amdgcn_global_load_lds(                      \
    (const __attribute__((address_space(1))) void*)(GP),                     \
    (__attribute__((address_space(3))) void*)(LP), 16, 0, 0)

__global__ __launch_bounds__(NTHREADS, 2)
void snn_v7(const float* __restrict__ x, float* __restrict__ out) {
    // Layout: granule (ci,row,gp) at byte ((ci*10+row)*16+gp)*16.
    // Slot gp holds SOURCE t-granule gp^(row&7)  (involution; read applies the
    // same XOR) -> per conv read-instr the 8 l-rows land on 8 distinct
    // bank-quads -> conflict-free. Staged via linear-dest global_load_lds with
    // inverse-swizzled per-lane SOURCE addresses (both-sides rule).
    __shared__ float4 xs[NGRAN];                     // exactly 81920 B

    const int tid  = threadIdx.x;
    const int l    = tid & 7;
    const int g    = (tid >> 3) & 7;                 // co-oct 0..7
    const int lane = tid & 63;
    const int tq2  = __builtin_amdgcn_readfirstlane(tid >> 6);  // t-quarter

    // XCD-chunked bijective remap (2048 blocks, %8==0): each XCD owns 256
    // consecutive wids = 2 full b-slices -> halo neighbors share an L2.
    const int lin = blockIdx.x;
    const int wid = (lin & 7) * 256 + (lin >> 3);
    const int b   = wid >> 7;
    const int lx  = wid & 127;
    const int l0  = lx * TL;
    const int lo  = l0 + l;

    const float* xb   = x   + (size_t)b * CIN * LEN * TT;
    float*       outb = out + (size_t)b * COUT * LEN * TT;

    // ---- staging descriptors: wave fills rounds [tq2*20, tq2*20+20)
    int off[RPW];
    unsigned okm = 0u;
    #pragma unroll
    for (int m = 0; m < RPW; ++m) {
        const int G   = (tq2 * RPW + m) * 64 + lane;  // granule this lane fills
        const int ci  = G / (HALO * 16);
        const int rem = G - ci * (HALO * 16);
        const int row = rem >> 4;
        const int gp  = rem & 15;
        const int tqs = gp ^ (row & 7);               // inverse swizzle
        const int lg  = l0 - 1 + row;
        const bool ok = (lg >= 0) && (lg < LEN);
        okm |= ok ? (1u << m) : 0u;
        off[m] = (ci * LEN + (ok ? lg : 0)) * TT + tqs * 4;
    }
    {   // issue all 20 loads; one barrier drains them
        char* lb = (char*)xs + tq2 * (RPW * 1024);
        #pragma unroll
        for (int m = 0; m < RPW; ++m) {
            const float* sp = (okm & (1u << m)) ? (xb + off[m]) : zeros_g;
            GLD16(sp, lb + m * 1024);
        }
    }
    __syncthreads();                                  // tile ready

    // ---- conv: EXACT chain order k outer, ci inner, sequential fmaf
    float acc[8][16];
    #pragma unroll
    for (int j = 0; j < 8; ++j)
        #pragma unroll
        for (int t = 0; t < 16; ++t) acc[j][t] = 0.f;

    const float* wq  = wpk8 + g * (KK * CIN * 8);     // per-lane base, imm offs
    const char*  xsb = (const char*)xs;

    #pragma unroll
    for (int k = 0; k < KK; ++k) {
        const int row = l + k;
        const int r7  = row & 7;
        const int rb  = row * 256;
        const char* a0 = xsb + rb + ((((tq2 * 4 + 0) ^ r7)) << 4);
        const char* a1 = xsb + rb + ((((tq2 * 4 + 1) ^ r7)) << 4);
        const char* a2 = xsb + rb + ((((tq2 * 4 + 2) ^ r7)) << 4);
        const char* a3 = xsb + rb + ((((tq2 * 4 + 3) ^ r7)) << 4);
        #pragma unroll 1
        for (int cic = 0; cic < 4; ++cic) {
            const float* wqa = wq + k * (CIN * 8) + cic * 64;
            #pragma unroll
            for (int c8 = 0; c8 < 8; ++c8) {
                const float4 x0 = *(const float4*)(a0 + c8 * 2560);
                const float4 x1 = *(const float4*)(a1 + c8 * 2560);
                const float4 x2 = *(const float4*)(a2 + c8 * 2560);
                const float4 x3 = *(const float4*)(a3 + c8 * 2560);
                const float4 wa = *(const float4*)(wqa + c8 * 8);
                const float4 wb = *(const float4*)(wqa + c8 * 8 + 4);
                #pragma unroll
                for (int j = 0; j < 8; ++j) {
                    const float w = (j == 0) ? wa.x : (j == 1) ? wa.y
                                  : (j == 2) ? wa.z : (j == 3) ? wa.w
                                  : (j == 4) ? wb.x : (j == 5) ? wb.y
                                  : (j == 6) ? wb.z : wb.w;
                    acc[j][ 0] = fmaf(x0.x, w, acc[j][ 0]);
                    acc[j][ 1] = fmaf(x0.y, w, acc[j][ 1]);
                    acc[j][ 2] = fmaf(x0.z, w, acc[j][ 2]);
                    acc[j][ 3] = fmaf(x0.w, w, acc[j][ 3]);
                    acc[j][ 4] = fmaf(x1.x, w, acc[j][ 4]);
                    acc[j][ 5] = fmaf(x1.y, w, acc[j][ 5]);
                    acc[j][ 6] = fmaf(x1.z, w, acc[j][ 6]);
                    acc[j][ 7] = fmaf(x1.w, w, acc[j][ 7]);
                    acc[j][ 8] = fmaf(x2.x, w, acc[j][ 8]);
                    acc[j][ 9] = fmaf(x2.y, w, acc[j][ 9]);
                    acc[j][10] = fmaf(x2.z, w, acc[j][10]);
                    acc[j][11] = fmaf(x2.w, w, acc[j][11]);
                    acc[j][12] = fmaf(x3.x, w, acc[j][12]);
                    acc[j][13] = fmaf(x3.y, w, acc[j][13]);
                    acc[j][14] = fmaf(x3.z, w, acc[j][14]);
                    acc[j][15] = fmaf(x3.w, w, acc[j][15]);
                }
            }
            a0 += 8 * 2560; a1 += 8 * 2560; a2 += 8 * 2560; a3 += 8 * 2560;
        }
    }

    // ---- LIF: wave w owns t in [w*16, w*16+16); pot handoff between waves
    // through a 2-KB overlay on the (now dead) x-tile. Each phase is FULLY
    // lane-parallel (no exec-mask dilution); 4 barriers total.
    __syncthreads();                 // all conv reads of xs complete
    float* potb = (float*)xs;        // 512 floats: slot = lane*8 + j

    float    pp[8];
    unsigned bits[8];

    #define LIF_SCAN(FIRST)                                                  \
        {   _Pragma("unroll")                                                \
            for (int j = 0; j < 8; ++j) {                                    \
                float p = (FIRST) ? 0.f : potb[lane * 8 + j];                \
                unsigned sb = 0u;                                            \
                _Pragma("unroll")                                            \
                for (int t = 0; t < 16; ++t) {                               \
                    const float s  = p + acc[j][t];                          \
                    const float q  = s * 0.9f;                               \
                    const bool  sp = (q >= 0.25f);                           \
                    sb |= sp ? (1u << t) : 0u;                               \
                    p = sp ? 0.f : q;                                        \
                }                                                            \
                pp[j] = p; bits[j] = sb;                                     \
            }                                                                \
        }
    #define POT_WRITE()                                                      \
        {   _Pragma("unroll")                                                \
            for (int j = 0; j < 8; ++j) potb[lane * 8 + j] = pp[j];          \
        }
    #define STORE_Q()                                                        \
        {   _Pragma("unroll")                                                \
            for (int j = 0; j < 8; ++j) {                                    \
                float* dst = outb + ((size_t)(g * 8 + j) * LEN + lo) * TT    \
                                  + tq2 * 16;                                \
                _Pragma("unroll")                                            \
                for (int q4 = 0; q4 < 4; ++q4) {                             \
                    const unsigned nib = bits[j] >> (q4 * 4);                \
                    *(float4*)(dst + q4 * 4) =                               \
                        make_float4(nib & 1u ? 1.f : 0.f,                    \
                                    nib & 2u ? 1.f : 0.f,                    \
                                    nib & 4u ? 1.f : 0.f,                    \
                                    nib & 8u ? 1.f : 0.f);                   \
                }                                                            \
            }                                                                \
        }

    if (tq2 == 0) { LIF_SCAN(true);  POT_WRITE(); STORE_Q(); }
    __syncthreads();
    if (tq2 == 1) { LIF_SCAN(false); POT_WRITE(); STORE_Q(); }
    __syncthreads();
    if (tq2 == 2) { LIF_SCAN(false); POT_WRITE(); STORE_Q(); }
    __syncthreads();
    if (tq2 == 3) { LIF_SCAN(false);              STORE_Q(); }
}

extern "C" void kernel_launch(void* const* d_in, const int* in_sizes, int n_in,
                              void* d_out, int out_size, void* d_ws, size_t ws_size,
                              hipStream_t stream) {
    const float* x = (const float*)d_in[0];   // (16, 32, 1024, 64) fp32
    const float* w = (const float*)d_in[1];   // (64, 32, 3) fp32
    float* out = (float*)d_out;               // (16, 64, 1024, 64) fp32
    (void)d_ws; (void)ws_size; (void)in_sizes; (void)n_in; (void)out_size;

    hipLaunchKernelGGL(repack_w, dim3(24), dim3(256), 0, stream, w);
    hipLaunchKernelGGL(snn_v7, dim3((LEN / TL) * BB), dim3(NTHREADS),
                       0, stream, x, out);
}

// Round 5
// 713.340 us; speedup vs baseline: 1.0143x; 1.0143x over previous
//
#include <hip/hip_runtime.h>

// Problem constants
#define BB    16
#define CIN   32
#define LEN   1024
#define TT    64
#define COUT  64
#define KK    3

// Tiling: thread = (co-oct g[3b], l); owns 8 co x 1 l x ALL 64 t.
// 4 stages of 16 t; conv per stage in two 8-t sub-passes (acc[8][8] = 64 regs);
// LIF fully thread-local (pot[8] across stages); spike bits -> blo/bhi[8];
// one epilogue writes each 256-B output row exactly once.
#define TL       16                  // l per block -> grid 64x16 = 1024 (4/CU)
#define HALO     18                  // TL + 2
#define NTHREADS 128                 // 2 waves; l = (tid&7) | (wave<<3)
#define NGRAN    (CIN * HALO * 4)    // 2304 16-B granules per stage (36864 B)
#define RPT      18                  // GLD16 per thread per stage (2304/128)

// INVARIANT (bit-exact vs np ref, proven in earlier rounds): per output cell
// the conv sum is ONE sequential fmaf chain, k outer (0..2), ci inner (0..31),
// acc=0; LIF fp32: s=pot+a; p=s*0.9f; spk=(p>=0.25f); pot=spk?0:p.
// OOB halo terms participate as fmaf(0,w,acc) == reference zero-pad.

// Packed weights: wpk8[((g*3+k)*32+ci)*8 + j] = w[(g*8+j)][ci][k]
__device__ float wpk8[COUT * CIN * KK];
// Zero page for out-of-range halo rows (never written -> stays 0).
__device__ float zeros_g[64];

__global__ void repack_w(const float* __restrict__ w) {
    const int i = blockIdx.x * 256 + threadIdx.x;     // 6144 total
    if (i < COUT * CIN * KK) {
        const int j  = i & 7;
        const int ci = (i >> 3) & 31;
        const int gk = i >> 8;                        // g*3 + k
        const int k  = gk % 3;
        const int g  = gk / 3;
        wpk8[i] = w[((g * 8 + j) * CIN + ci) * KK + k];
    }
}

// 16-B async global->LDS (dest = wave-uniform base + lane*16; source per-lane).
#define GLD16(GP, LP) __builtin_amdgcn_global_load_lds(                      \
    (const __attribute__((address_space(1))) void*)(GP),                     \
    (__attribute__((address_space(3))) void*)(LP), 16, 0, 0)

__global__ __launch_bounds__(NTHREADS, 2)
void snn_v8(const float* __restrict__ x, float* __restrict__ out) {
    // Stage tile, granule (ci,row,gp) at byte ((ci*18+row)*4 + gp)*16; slot gp
    // holds SOURCE t-granule gp^(row&3) (involution; reads apply same XOR).
    // Conv read (fixed k,ci,slot): 8 l-rows at 64-B stride, XOR-spread -> every
    // 128-B bank cycle serves exactly 2 lanes -> 2-way (free, m136).
    __shared__ float4 xs[NGRAN];                      // 36864 B -> 4 blocks/CU

    const int tid  = threadIdx.x;
    const int g    = (tid >> 3) & 7;                  // co-oct 0..7
    const int l    = (tid & 7) | ((tid >> 6) << 3);   // wave supplies l-octave
    const int lane = tid & 63;
    const int wv   = __builtin_amdgcn_readfirstlane(tid >> 6);   // 0..1

    // XCD-chunked bijective remap (1024 blocks, %8==0): each XCD gets 128
    // consecutive wids = 2 full b-slices -> halo/L2 locality.
    const int lin = blockIdx.x;
    const int wid = (lin & 7) * 128 + (lin >> 3);
    const int b   = wid >> 6;
    const int lx  = wid & 63;
    const int l0  = lx * TL;
    const int lo  = l0 + l;

    const float* xb   = x   + (size_t)b * CIN * LEN * TT;
    float*       outb = out + (size_t)b * COUT * LEN * TT;

    // ---- staging descriptors (base = stage 0; stage sc adds sc*16 floats)
    int goff[RPT];
    unsigned okm = 0u;
    #pragma unroll
    for (int m = 0; m < RPT; ++m) {
        const int G   = (wv * RPT + m) * 64 + lane;   // granule this lane fills
        const int ci  = G / (HALO * 4);
        const int rem = G - ci * (HALO * 4);
        const int row = rem >> 2;
        const int gp  = rem & 3;
        const int ts  = gp ^ (row & 3);               // inverse swizzle
        const int lg  = l0 - 1 + row;
        const bool ok = (lg >= 0) && (lg < LEN);
        okm |= ok ? (1u << m) : 0u;
        goff[m] = (ci * LEN + (ok ? lg : 0)) * TT + ts * 4;
    }

    float    pot[8];
    unsigned blo[8], bhi[8];
    #pragma unroll
    for (int j = 0; j < 8; ++j) { pot[j] = 0.f; blo[j] = 0u; bhi[j] = 0u; }

    const float* wg  = wpk8 + g * (KK * CIN * 8);     // per-lane, L1-broadcast
    const char*  xsb = (const char*)xs;

    #pragma unroll 1
    for (int sc = 0; sc < 4; ++sc) {
        if (sc) __syncthreads();                      // readers of sc-1 done
        {   // refill single buffer for this stage
            char* lb = (char*)xs + (wv * RPT) * 1024;
            #pragma unroll
            for (int m = 0; m < RPT; ++m) {
                const float* sp = (okm & (1u << m)) ? (xb + goff[m] + sc * 16)
                                                    : zeros_g;
                GLD16(sp, lb + m * 1024);
            }
        }
        __syncthreads();               // vmcnt(0)+barrier: tile ready

        unsigned stb[8];
        #pragma unroll
        for (int j = 0; j < 8; ++j) stb[j] = 0u;

        // two 8-t sub-passes; s2 passed as literal -> constant-folds
        auto subpass = [&](int s2) {
            float acc[8][8];
            #pragma unroll
            for (int j = 0; j < 8; ++j)
                #pragma unroll
                for (int i = 0; i < 8; ++i) acc[j][i] = 0.f;

            // conv: EXACT chain order k outer, ci inner, sequential fmaf
            #pragma unroll 1
            for (int k = 0; k < KK; ++k) {
                const int rowk = l + k;
                const int sw   = rowk & 3;
                const char* a0 = xsb + rowk * 64 + (((s2 * 2 + 0) ^ sw) << 4);
                const char* a1 = xsb + rowk * 64 + (((s2 * 2 + 1) ^ sw) << 4);
                const float* wk = wg + k * (CIN * 8);
                #pragma unroll 1
                for (int cic = 0; cic < 4; ++cic) {
                    #pragma unroll
                    for (int c8 = 0; c8 < 8; ++c8) {
                        const int ci = cic * 8 + c8;
                        const float4 x0 = *(const float4*)(a0 + ci * 1152);
                        const float4 x1 = *(const float4*)(a1 + ci * 1152);
                        const float4 wa = *(const float4*)(wk + ci * 8);
                        const float4 wb = *(const float4*)(wk + ci * 8 + 4);
                        #pragma unroll
                        for (int j = 0; j < 8; ++j) {
                            const float w = (j == 0) ? wa.x : (j == 1) ? wa.y
                                          : (j == 2) ? wa.z : (j == 3) ? wa.w
                                          : (j == 4) ? wb.x : (j == 5) ? wb.y
                                          : (j == 6) ? wb.z : wb.w;
                            acc[j][0] = fmaf(x0.x, w, acc[j][0]);
                            acc[j][1] = fmaf(x0.y, w, acc[j][1]);
                            acc[j][2] = fmaf(x0.z, w, acc[j][2]);
                            acc[j][3] = fmaf(x0.w, w, acc[j][3]);
                            acc[j][4] = fmaf(x1.x, w, acc[j][4]);
                            acc[j][5] = fmaf(x1.y, w, acc[j][5]);
                            acc[j][6] = fmaf(x1.z, w, acc[j][6]);
                            acc[j][7] = fmaf(x1.w, w, acc[j][7]);
                        }
                    }
                }
            }

            // LIF: thread-local, t ascending (bit = s2*8+i, compile-time)
            #pragma unroll
            for (int j = 0; j < 8; ++j) {
                float p = pot[j];
                unsigned sb = 0u;
                #pragma unroll
                for (int i = 0; i < 8; ++i) {
                    const float s  = p + acc[j][i];
                    const float q  = s * 0.9f;
                    const bool  sp = (q >= 0.25f);
                    sb |= sp ? (1u << (s2 * 8 + i)) : 0u;
                    p = sp ? 0.f : q;
                }
                pot[j] = p;
                stb[j] |= sb;
            }
        };
        subpass(0);
        subpass(1);

        // merge this stage's 16 bits into the 64-bit masks (uniform sc branch)
        const unsigned sh = (unsigned)((sc & 1) * 16);
        if (sc < 2) {
            #pragma unroll
            for (int j = 0; j < 8; ++j) blo[j] |= stb[j] << sh;
        } else {
            #pragma unroll
            for (int j = 0; j < 8; ++j) bhi[j] |= stb[j] << sh;
        }
    }

    // ---- epilogue: each thread writes its 8 full 256-B rows exactly once
    #pragma unroll
    for (int j = 0; j < 8; ++j) {
        float* dst = outb + ((size_t)(g * 8 + j) * LEN + lo) * TT;
        const unsigned wlo = blo[j], whi = bhi[j];
        #pragma unroll
        for (int q = 0; q < 16; ++q) {
            const unsigned word = (q < 8) ? wlo : whi;
            const unsigned nib  = word >> ((q & 7) * 4);
            *(float4*)(dst + q * 4) = make_float4(nib & 1u ? 1.f : 0.f,
                                                  nib & 2u ? 1.f : 0.f,
                                                  nib & 4u ? 1.f : 0.f,
                                                  nib & 8u ? 1.f : 0.f);
        }
    }
}

extern "C" void kernel_launch(void* const* d_in, const int* in_sizes, int n_in,
                              void* d_out, int out_size, void* d_ws, size_t ws_size,
                              hipStream_t stream) {
    const float* x = (const float*)d_in[0];   // (16, 32, 1024, 64) fp32
    const float* w = (const float*)d_in[1];   // (64, 32, 3) fp32
    float* out = (float*)d_out;               // (16, 64, 1024, 64) fp32
    (void)d_ws; (void)ws_size; (void)in_sizes; (void)n_in; (void)out_size;

    hipLaunchKernelGGL(repack_w, dim3(24), dim3(256), 0, stream, w);
    hipLaunchKernelGGL(snn_v8, dim3((LEN / TL) * BB), dim3(NTHREADS),
                       0, stream, x, out);
}